// Round 1
// baseline (116.763 us; speedup 1.0000x reference)
//
#include <hip/hip_runtime.h>
#include <hip/hip_bf16.h>

typedef __attribute__((ext_vector_type(8))) short short8;
typedef __attribute__((ext_vector_type(4))) float f32x4;

#define MAXNBR 128
#define ALPHA 0.2f

static __device__ __forceinline__ unsigned short f2bf(float f) {
    union { float f; unsigned u; } v; v.f = f;
    unsigned r = v.u + 0x7FFF + ((v.u >> 16) & 1);
    return (unsigned short)(r >> 16);
}

// ---------- K0a: x fp32 -> bf16 ----------
__global__ __launch_bounds__(256) void cvt_x(const float* __restrict__ x,
                                             unsigned short* __restrict__ xb) {
    int idx = blockIdx.x * 256 + threadIdx.x;   // one per 4 elems
    float4 v = *(const float4*)&x[(size_t)idx * 4];
    ushort4 o;
    o.x = f2bf(v.x); o.y = f2bf(v.y); o.z = f2bf(v.z); o.w = f2bf(v.w);
    *(ushort4*)&xb[(size_t)idx * 4] = o;
}

// ---------- K0b: W1 [512][1024] fp32 -> W1t [1024][512] bf16 (transposed) ----------
__global__ __launch_bounds__(256) void cvt_w1t(const float* __restrict__ W1,
                                               unsigned short* __restrict__ W1t) {
    int idx = blockIdx.x * 256 + threadIdx.x;   // output index c*512+k
    int c = idx >> 9, k = idx & 511;
    W1t[idx] = f2bf(W1[(size_t)k * 1024 + c]);
}

// ---------- K_adj: extract neighbor lists (deterministic, ballot-based) ----------
__global__ __launch_bounds__(256) void build_adj(const float* __restrict__ adj,
                                                 int* __restrict__ nbr_idx,
                                                 int* __restrict__ nbr_cnt) {
    int row = blockIdx.x * 4 + (threadIdx.x >> 6);
    int lane = threadIdx.x & 63;
    const float* arow = adj + (size_t)row * 4096;
    int cnt = 0;
    for (int base = 0; base < 4096; base += 256) {
        float4 v = *(const float4*)&arow[base + lane * 4];
        #pragma unroll
        for (int s = 0; s < 4; ++s) {
            float xv = ((const float*)&v)[s];
            unsigned long long m = __ballot(xv > 0.f);
            if (xv > 0.f) {
                int pos = cnt + (int)__popcll(m & ((1ull << lane) - 1ull));
                if (pos < MAXNBR) nbr_idx[row * MAXNBR + pos] = base + lane * 4 + s;
            }
            cnt += (int)__popcll(m);
        }
    }
    if (lane == 0) nbr_cnt[row] = cnt < MAXNBR ? cnt : MAXNBR;
}

// ---------- K1: h1[4096][1024] = x_bf[4096][512] @ W1 (via W1t bf16) ----------
__global__ __launch_bounds__(256) void gemm1(const unsigned short* __restrict__ A,
                                             const unsigned short* __restrict__ Bt,
                                             float* __restrict__ C) {
    __shared__ unsigned short Asm[128][64];
    __shared__ unsigned short Bsm[128][64];
    int tid = threadIdx.x;
    int lane = tid & 63;
    int w = tid >> 6;
    int wr = w >> 1, wc = w & 1;
    int rowBase = blockIdx.x * 128, colBase = blockIdx.y * 128;
    f32x4 acc[4][4] = {};
    for (int k0 = 0; k0 < 512; k0 += 64) {
        for (int c = tid; c < 128 * 64 / 8; c += 256) {
            int r = c >> 3, kc = (c & 7) * 8;
            *(short8*)&Asm[r][kc] = *(const short8*)&A[(size_t)(rowBase + r) * 512 + k0 + kc];
            *(short8*)&Bsm[r][kc] = *(const short8*)&Bt[(size_t)(colBase + r) * 512 + k0 + kc];
        }
        __syncthreads();
        #pragma unroll
        for (int kk = 0; kk < 64; kk += 32) {
            short8 af[4], bf[4];
            int kfrag = kk + (lane >> 4) * 8;
            #pragma unroll
            for (int m = 0; m < 4; ++m)
                af[m] = *(const short8*)&Asm[wr * 64 + m * 16 + (lane & 15)][kfrag];
            #pragma unroll
            for (int n = 0; n < 4; ++n)
                bf[n] = *(const short8*)&Bsm[wc * 64 + n * 16 + (lane & 15)][kfrag];
            #pragma unroll
            for (int m = 0; m < 4; ++m)
                #pragma unroll
                for (int n = 0; n < 4; ++n)
                    acc[m][n] = __builtin_amdgcn_mfma_f32_16x16x32_bf16(af[m], bf[n], acc[m][n], 0, 0, 0);
        }
        __syncthreads();
    }
    int crow0 = rowBase + wr * 64, ccol0 = colBase + wc * 64;
    #pragma unroll
    for (int m = 0; m < 4; ++m)
        #pragma unroll
        for (int n = 0; n < 4; ++n) {
            int col = ccol0 + n * 16 + (lane & 15);
            int row0 = crow0 + m * 16 + (lane >> 4) * 4;
            #pragma unroll
            for (int r = 0; r < 4; ++r)
                C[(size_t)(row0 + r) * 1024 + col] = acc[m][n][r];
        }
}

// ---------- K2: f_src1/f_dst1 [8][4096] ----------
__global__ __launch_bounds__(256) void attn_coef1(const float* __restrict__ h1,
                                                  const float* __restrict__ a_src,
                                                  const float* __restrict__ a_dst,
                                                  float* __restrict__ f_src,
                                                  float* __restrict__ f_dst) {
    int n = blockIdx.x, t = threadIdx.x;
    float4 v = *(const float4*)&h1[(size_t)n * 1024 + t * 4];
    int head = t >> 5;
    int o0 = (t * 4) & 127;
    float ps = 0.f, pd = 0.f;
    #pragma unroll
    for (int i = 0; i < 4; ++i) {
        float hv = ((const float*)&v)[i];
        ps += hv * a_src[head * 128 + o0 + i];
        pd += hv * a_dst[head * 128 + o0 + i];
    }
    #pragma unroll
    for (int off = 1; off < 32; off <<= 1) {
        ps += __shfl_xor(ps, off);
        pd += __shfl_xor(pd, off);
    }
    if ((t & 31) == 0) {
        f_src[head * 4096 + n] = ps;
        f_dst[head * 4096 + n] = pd;
    }
}

// ---------- K3: layer-1 masked softmax + aggregation + elu ----------
__global__ __launch_bounds__(256) void aggregate1(const float* __restrict__ h1,
                                                  const int* __restrict__ nbr_idx,
                                                  const int* __restrict__ nbr_cnt,
                                                  const float* __restrict__ f_src,
                                                  const float* __restrict__ f_dst,
                                                  float* __restrict__ h1act) {
    __shared__ int nbr[MAXNBR];
    __shared__ float attn[8][MAXNBR];
    __shared__ float fs[8];
    __shared__ float red[8][2];
    int i = blockIdx.x;
    int t = threadIdx.x;
    int cnt = nbr_cnt[i];
    if (t < cnt) nbr[t] = nbr_idx[i * MAXNBR + t];
    if (t < 8) fs[t] = f_src[t * 4096 + i];
    __syncthreads();
    for (int p = t; p < 8 * MAXNBR; p += 256) {
        int h = p >> 7, j = p & 127;
        float e = -INFINITY;
        if (j < cnt) {
            float x = fs[h] + f_dst[h * 4096 + nbr[j]];
            e = x > 0.f ? x : ALPHA * x;
        }
        attn[h][j] = e;
    }
    __syncthreads();
    {
        int h = t >> 5, il = t & 31;
        float m = -INFINITY;
        for (int j = il; j < MAXNBR; j += 32) m = fmaxf(m, attn[h][j]);
        #pragma unroll
        for (int off = 1; off < 32; off <<= 1) m = fmaxf(m, __shfl_xor(m, off));
        float s = 0.f;
        for (int j = il; j < MAXNBR; j += 32) {
            float e = attn[h][j];
            if (e != -INFINITY) s += __expf(e - m);
        }
        #pragma unroll
        for (int off = 1; off < 32; off <<= 1) s += __shfl_xor(s, off);
        if (il == 0) { red[h][0] = m; red[h][1] = s; }
    }
    __syncthreads();
    for (int p = t; p < 8 * MAXNBR; p += 256) {
        int h = p >> 7, j = p & 127;
        float e = attn[h][j];
        attn[h][j] = (e == -INFINITY) ? 0.f : __expf(e - red[h][0]) / red[h][1];
    }
    __syncthreads();
    #pragma unroll
    for (int r = 0; r < 4; ++r) {
        int f = t + r * 256;
        int h = f >> 7;
        float acc = 0.f;
        for (int j = 0; j < cnt; ++j)
            acc += attn[h][j] * h1[(size_t)nbr[j] * 1024 + f];
        h1act[(size_t)i * 1024 + f] = acc > 0.f ? acc : expm1f(acc);
    }
}

// ---------- K4: h2 = h1act @ W2 [1024][16], plus f_src2/f_dst2 ----------
__global__ __launch_bounds__(256) void layer2_gemm(const float* __restrict__ h1act,
                                                   const float* __restrict__ W2,
                                                   const float* __restrict__ a_src2,
                                                   const float* __restrict__ a_dst2,
                                                   float* __restrict__ h2,
                                                   float* __restrict__ f_src2,
                                                   float* __restrict__ f_dst2) {
    __shared__ float row[1024];
    __shared__ float partial[16][16];
    __shared__ float h2row[16];
    int n = blockIdx.x, t = threadIdx.x;
    *(float4*)&row[t * 4] = *(const float4*)&h1act[(size_t)n * 1024 + t * 4];
    __syncthreads();
    int o = t & 15, seg = t >> 4;
    float acc = 0.f;
    for (int k = seg * 64; k < seg * 64 + 64; ++k)
        acc += row[k] * W2[k * 16 + o];
    partial[seg][o] = acc;
    __syncthreads();
    if (t < 16) {
        float s = 0.f;
        #pragma unroll
        for (int g = 0; g < 16; ++g) s += partial[g][t];
        h2[n * 16 + t] = s;
        h2row[t] = s;
    }
    __syncthreads();
    if (t < 16) {
        float ps = h2row[t] * a_src2[t];
        float pd = h2row[t] * a_dst2[t];
        #pragma unroll
        for (int off = 1; off < 16; off <<= 1) {
            ps += __shfl_xor(ps, off);
            pd += __shfl_xor(pd, off);
        }
        if (t == 0) { f_src2[n] = ps; f_dst2[n] = pd; }
    }
}

// ---------- K5: layer-2 aggregation + elu + log_softmax ----------
__global__ __launch_bounds__(64) void final_layer(const float* __restrict__ h2,
                                                  const int* __restrict__ nbr_idx,
                                                  const int* __restrict__ nbr_cnt,
                                                  const float* __restrict__ f_src2,
                                                  const float* __restrict__ f_dst2,
                                                  float* __restrict__ out) {
    __shared__ float attn[MAXNBR];
    __shared__ int nbr[MAXNBR];
    int i = blockIdx.x;
    int l = threadIdx.x;
    int cnt = nbr_cnt[i];
    float fsi = f_src2[i];
    for (int j = l; j < MAXNBR; j += 64) {
        float e = -INFINITY;
        if (j < cnt) {
            int jj = nbr_idx[i * MAXNBR + j];
            nbr[j] = jj;
            float x = fsi + f_dst2[jj];
            e = x > 0.f ? x : ALPHA * x;
        }
        attn[j] = e;
    }
    __syncthreads();
    float m = fmaxf(attn[l], attn[l + 64]);
    #pragma unroll
    for (int off = 1; off < 64; off <<= 1) m = fmaxf(m, __shfl_xor(m, off));
    float s = 0.f;
    {
        float e0 = attn[l], e1 = attn[l + 64];
        if (e0 != -INFINITY) s += __expf(e0 - m);
        if (e1 != -INFINITY) s += __expf(e1 - m);
    }
    #pragma unroll
    for (int off = 1; off < 64; off <<= 1) s += __shfl_xor(s, off);
    for (int j = l; j < MAXNBR; j += 64) {
        float e = attn[j];
        attn[j] = (e == -INFINITY) ? 0.f : __expf(e - m) / s;
    }
    __syncthreads();
    if (l < 16) {
        float acc = 0.f;
        for (int j = 0; j < cnt; ++j)
            acc += attn[j] * h2[nbr[j] * 16 + l];
        float v = acc > 0.f ? acc : expm1f(acc);
        float mx = v;
        #pragma unroll
        for (int off = 1; off < 16; off <<= 1) mx = fmaxf(mx, __shfl_xor(mx, off));
        float se = __expf(v - mx);
        #pragma unroll
        for (int off = 1; off < 16; off <<= 1) se += __shfl_xor(se, off);
        out[i * 16 + l] = v - mx - logf(se);
    }
}

extern "C" void kernel_launch(void* const* d_in, const int* in_sizes, int n_in,
                              void* d_out, int out_size, void* d_ws, size_t ws_size,
                              hipStream_t stream) {
    const float* x      = (const float*)d_in[0];
    const float* adj    = (const float*)d_in[1];
    const float* W1     = (const float*)d_in[2];
    const float* a_src1 = (const float*)d_in[3];
    const float* a_dst1 = (const float*)d_in[4];
    const float* W2     = (const float*)d_in[5];
    const float* a_src2 = (const float*)d_in[6];
    const float* a_dst2 = (const float*)d_in[7];
    float* out = (float*)d_out;

    char* ws = (char*)d_ws;
    unsigned short* xb   = (unsigned short*)ws;                       // 4 MB
    unsigned short* w1t  = (unsigned short*)(ws + (4u << 20));        // 1 MB
    float* h1    = (float*)(ws + (5u << 20));                         // 16 MB
    float* h1act = (float*)(ws + (21u << 20));                        // 16 MB
    float* fsrc1 = (float*)(ws + (37u << 20));                        // 128 KB
    float* fdst1 = (float*)(ws + (37u << 20) + (128u << 10));         // 128 KB
    float* h2    = (float*)(ws + (38u << 20));                        // 256 KB
    float* fsrc2 = (float*)(ws + (38u << 20) + (256u << 10));         // 16 KB
    float* fdst2 = (float*)(ws + (38u << 20) + (272u << 10));         // 16 KB
    int* nbr_idx = (int*)(ws + (39u << 20));                          // 2 MB
    int* nbr_cnt = (int*)(ws + (41u << 20));                          // 16 KB

    build_adj<<<1024, 256, 0, stream>>>(adj, nbr_idx, nbr_cnt);
    cvt_x<<<2048, 256, 0, stream>>>(x, xb);
    cvt_w1t<<<2048, 256, 0, stream>>>(W1, w1t);
    gemm1<<<dim3(32, 8), 256, 0, stream>>>(xb, w1t, h1);
    attn_coef1<<<4096, 256, 0, stream>>>(h1, a_src1, a_dst1, fsrc1, fdst1);
    aggregate1<<<4096, 256, 0, stream>>>(h1, nbr_idx, nbr_cnt, fsrc1, fdst1, h1act);
    layer2_gemm<<<4096, 256, 0, stream>>>(h1act, W2, a_src2, a_dst2, h2, fsrc2, fdst2);
    final_layer<<<4096, 64, 0, stream>>>(h2, nbr_idx, nbr_cnt, fsrc2, fdst2, out);
}

// Round 2
// 85.176 us; speedup vs baseline: 1.3708x; 1.3708x over previous
//
#include <hip/hip_runtime.h>
#include <hip/hip_bf16.h>

typedef __attribute__((ext_vector_type(8))) short short8;
typedef __attribute__((ext_vector_type(4))) float f32x4;

#define MAXNBR 128
#define ALPHA 0.2f

static __device__ __forceinline__ unsigned short f2bf(float f) {
    union { float f; unsigned u; } v; v.f = f;
    unsigned r = v.u + 0x7FFF + ((v.u >> 16) & 1);
    return (unsigned short)(r >> 16);
}
static __device__ __forceinline__ float bf2f(unsigned short u) {
    union { unsigned u; float f; } v; v.u = ((unsigned)u) << 16;
    return v.f;
}

// ---------- K0: x fp32 -> bf16  AND  W1 [512][1024] -> W1t [1024][512] bf16 ----------
__global__ __launch_bounds__(256) void cvt_inputs(const float* __restrict__ x,
                                                  unsigned short* __restrict__ xb,
                                                  const float* __restrict__ W1,
                                                  unsigned short* __restrict__ W1t) {
    int b = blockIdx.x;
    if (b < 2048) {
        int idx = b * 256 + threadIdx.x;   // one per 4 elems of x
        float4 v = *(const float4*)&x[(size_t)idx * 4];
        ushort4 o;
        o.x = f2bf(v.x); o.y = f2bf(v.y); o.z = f2bf(v.z); o.w = f2bf(v.w);
        *(ushort4*)&xb[(size_t)idx * 4] = o;
    } else {
        int idx = (b - 2048) * 256 + threadIdx.x;  // output index c*512+k
        int c = idx >> 9, k = idx & 511;
        W1t[idx] = f2bf(W1[(size_t)k * 1024 + c]);
    }
}

// ---------- K_adj: extract neighbor lists (deterministic, ballot-based) ----------
__global__ __launch_bounds__(256) void build_adj(const float* __restrict__ adj,
                                                 int* __restrict__ nbr_idx,
                                                 int* __restrict__ nbr_cnt) {
    int row = blockIdx.x * 4 + (threadIdx.x >> 6);
    int lane = threadIdx.x & 63;
    const float* arow = adj + (size_t)row * 4096;
    int cnt = 0;
    for (int base = 0; base < 4096; base += 256) {
        float4 v = *(const float4*)&arow[base + lane * 4];
        #pragma unroll
        for (int s = 0; s < 4; ++s) {
            float xv = ((const float*)&v)[s];
            unsigned long long m = __ballot(xv > 0.f);
            if (xv > 0.f) {
                int pos = cnt + (int)__popcll(m & ((1ull << lane) - 1ull));
                if (pos < MAXNBR) nbr_idx[row * MAXNBR + pos] = base + lane * 4 + s;
            }
            cnt += (int)__popcll(m);
        }
    }
    if (lane == 0) nbr_cnt[row] = cnt < MAXNBR ? cnt : MAXNBR;
}

// ---------- K1: h1b[4096][1024] bf16 = xb[4096][512] @ W1 (via W1t bf16) ----------
__global__ __launch_bounds__(256) void gemm1(const unsigned short* __restrict__ A,
                                             const unsigned short* __restrict__ Bt,
                                             unsigned short* __restrict__ C) {
    __shared__ unsigned short Asm[128 * 64];
    __shared__ unsigned short Bsm[128 * 64];
    int tid = threadIdx.x;
    int lane = tid & 63;
    int w = tid >> 6;
    int wr = w >> 1, wc = w & 1;
    int rowBase = blockIdx.x * 128, colBase = blockIdx.y * 128;
    int lr = lane >> 3;         // row within 8-row group
    int lc = (lane & 7) * 8;    // col 0..56 (bf16 units)
    f32x4 acc[4][4] = {};
    for (int k0 = 0; k0 < 512; k0 += 64) {
        #pragma unroll
        for (int i = 0; i < 4; ++i) {
            int rA = i * 32 + w * 8;   // wave-uniform LDS row base
            __builtin_amdgcn_global_load_lds(
                (const __attribute__((address_space(1))) void*)&A[(size_t)(rowBase + rA + lr) * 512 + k0 + lc],
                (__attribute__((address_space(3))) void*)&Asm[rA * 64],
                16, 0, 0);
            __builtin_amdgcn_global_load_lds(
                (const __attribute__((address_space(1))) void*)&Bt[(size_t)(colBase + rA + lr) * 512 + k0 + lc],
                (__attribute__((address_space(3))) void*)&Bsm[rA * 64],
                16, 0, 0);
        }
        __syncthreads();
        #pragma unroll
        for (int kk = 0; kk < 64; kk += 32) {
            short8 af[4], bfv[4];
            int kf = kk + (lane >> 4) * 8;
            #pragma unroll
            for (int m = 0; m < 4; ++m)
                af[m] = *(const short8*)&Asm[(wr * 64 + m * 16 + (lane & 15)) * 64 + kf];
            #pragma unroll
            for (int n = 0; n < 4; ++n)
                bfv[n] = *(const short8*)&Bsm[(wc * 64 + n * 16 + (lane & 15)) * 64 + kf];
            #pragma unroll
            for (int m = 0; m < 4; ++m)
                #pragma unroll
                for (int n = 0; n < 4; ++n)
                    acc[m][n] = __builtin_amdgcn_mfma_f32_16x16x32_bf16(af[m], bfv[n], acc[m][n], 0, 0, 0);
        }
        __syncthreads();
    }
    int crow0 = rowBase + wr * 64, ccol0 = colBase + wc * 64;
    #pragma unroll
    for (int m = 0; m < 4; ++m)
        #pragma unroll
        for (int n = 0; n < 4; ++n) {
            int col = ccol0 + n * 16 + (lane & 15);
            int row0 = crow0 + m * 16 + (lane >> 4) * 4;
            #pragma unroll
            for (int r = 0; r < 4; ++r)
                C[(size_t)(row0 + r) * 1024 + col] = f2bf(acc[m][n][r]);
        }
}

// ---------- K2: f_src1/f_dst1 [8][4096] from bf16 h1 ----------
__global__ __launch_bounds__(256) void attn_coef1(const unsigned short* __restrict__ h1b,
                                                  const float* __restrict__ a_src,
                                                  const float* __restrict__ a_dst,
                                                  float* __restrict__ f_src,
                                                  float* __restrict__ f_dst) {
    int n = blockIdx.x, t = threadIdx.x;
    ushort4 v = *(const ushort4*)&h1b[(size_t)n * 1024 + t * 4];
    int head = t >> 5;
    int o0 = (t * 4) & 127;
    float hv0 = bf2f(v.x), hv1 = bf2f(v.y), hv2 = bf2f(v.z), hv3 = bf2f(v.w);
    float ps = hv0 * a_src[head * 128 + o0] + hv1 * a_src[head * 128 + o0 + 1]
             + hv2 * a_src[head * 128 + o0 + 2] + hv3 * a_src[head * 128 + o0 + 3];
    float pd = hv0 * a_dst[head * 128 + o0] + hv1 * a_dst[head * 128 + o0 + 1]
             + hv2 * a_dst[head * 128 + o0 + 2] + hv3 * a_dst[head * 128 + o0 + 3];
    #pragma unroll
    for (int off = 1; off < 32; off <<= 1) {
        ps += __shfl_xor(ps, off);
        pd += __shfl_xor(pd, off);
    }
    if ((t & 31) == 0) {
        f_src[head * 4096 + n] = ps;
        f_dst[head * 4096 + n] = pd;
    }
}

// ---------- K3: layer-1 masked softmax + aggregation + elu (bf16 in/out) ----------
__global__ __launch_bounds__(256) void aggregate1(const unsigned short* __restrict__ h1b,
                                                  const int* __restrict__ nbr_idx,
                                                  const int* __restrict__ nbr_cnt,
                                                  const float* __restrict__ f_src,
                                                  const float* __restrict__ f_dst,
                                                  unsigned short* __restrict__ h1act) {
    __shared__ int nbr[MAXNBR];
    __shared__ float attw[8][MAXNBR];
    __shared__ float fs[8];
    __shared__ float red[8][2];
    int i = blockIdx.x;
    int t = threadIdx.x;
    int cnt = nbr_cnt[i];
    if (t < cnt) nbr[t] = nbr_idx[i * MAXNBR + t];
    if (t < 8) fs[t] = f_src[t * 4096 + i];
    __syncthreads();
    for (int p = t; p < 8 * MAXNBR; p += 256) {
        int h = p >> 7, j = p & 127;
        float e = -INFINITY;
        if (j < cnt) {
            float x = fs[h] + f_dst[h * 4096 + nbr[j]];
            e = x > 0.f ? x : ALPHA * x;
        }
        attw[h][j] = e;
    }
    __syncthreads();
    {
        int h = t >> 5, il = t & 31;
        float m = -INFINITY;
        for (int j = il; j < MAXNBR; j += 32) m = fmaxf(m, attw[h][j]);
        #pragma unroll
        for (int off = 1; off < 32; off <<= 1) m = fmaxf(m, __shfl_xor(m, off));
        float s = 0.f;
        for (int j = il; j < MAXNBR; j += 32) {
            float e = attw[h][j];
            if (e != -INFINITY) s += __expf(e - m);
        }
        #pragma unroll
        for (int off = 1; off < 32; off <<= 1) s += __shfl_xor(s, off);
        if (il == 0) { red[h][0] = m; red[h][1] = s; }
    }
    __syncthreads();
    for (int p = t; p < 8 * MAXNBR; p += 256) {
        int h = p >> 7, j = p & 127;
        float e = attw[h][j];
        attw[h][j] = (e == -INFINITY) ? 0.f : __expf(e - red[h][0]) / red[h][1];
    }
    __syncthreads();
    // thread t owns features t*4 .. t*4+3 (all in head t>>5)
    int h = t >> 5;
    const unsigned short* src = h1b + t * 4;
    float a0 = 0.f, a1 = 0.f, a2 = 0.f, a3 = 0.f;
    for (int j = 0; j < cnt; ++j) {
        float wgt = attw[h][j];
        ushort4 v = *(const ushort4*)&src[(size_t)nbr[j] * 1024];
        a0 += wgt * bf2f(v.x);
        a1 += wgt * bf2f(v.y);
        a2 += wgt * bf2f(v.z);
        a3 += wgt * bf2f(v.w);
    }
    a0 = a0 > 0.f ? a0 : expm1f(a0);
    a1 = a1 > 0.f ? a1 : expm1f(a1);
    a2 = a2 > 0.f ? a2 : expm1f(a2);
    a3 = a3 > 0.f ? a3 : expm1f(a3);
    ushort4 o;
    o.x = f2bf(a0); o.y = f2bf(a1); o.z = f2bf(a2); o.w = f2bf(a3);
    *(ushort4*)&h1act[(size_t)i * 1024 + t * 4] = o;
}

// ---------- K4: h2 = h1act @ W2 [1024][16], plus f_src2/f_dst2 ----------
__global__ __launch_bounds__(256) void layer2_gemm(const unsigned short* __restrict__ h1act,
                                                   const float* __restrict__ W2,
                                                   const float* __restrict__ a_src2,
                                                   const float* __restrict__ a_dst2,
                                                   float* __restrict__ h2,
                                                   float* __restrict__ f_src2,
                                                   float* __restrict__ f_dst2) {
    __shared__ float row[1024];
    __shared__ float partial[16][16];
    __shared__ float h2row[16];
    int n = blockIdx.x, t = threadIdx.x;
    {
        ushort4 v = *(const ushort4*)&h1act[(size_t)n * 1024 + t * 4];
        row[t * 4]     = bf2f(v.x);
        row[t * 4 + 1] = bf2f(v.y);
        row[t * 4 + 2] = bf2f(v.z);
        row[t * 4 + 3] = bf2f(v.w);
    }
    __syncthreads();
    int o = t & 15, seg = t >> 4;
    float acc = 0.f;
    for (int k = seg * 64; k < seg * 64 + 64; ++k)
        acc += row[k] * W2[k * 16 + o];
    partial[seg][o] = acc;
    __syncthreads();
    if (t < 16) {
        float s = 0.f;
        #pragma unroll
        for (int g = 0; g < 16; ++g) s += partial[g][t];
        h2[n * 16 + t] = s;
        h2row[t] = s;
    }
    __syncthreads();
    if (t < 16) {
        float ps = h2row[t] * a_src2[t];
        float pd = h2row[t] * a_dst2[t];
        #pragma unroll
        for (int off = 1; off < 16; off <<= 1) {
            ps += __shfl_xor(ps, off);
            pd += __shfl_xor(pd, off);
        }
        if (t == 0) { f_src2[n] = ps; f_dst2[n] = pd; }
    }
}

// ---------- K5: layer-2 aggregation + elu + log_softmax ----------
__global__ __launch_bounds__(64) void final_layer(const float* __restrict__ h2,
                                                  const int* __restrict__ nbr_idx,
                                                  const int* __restrict__ nbr_cnt,
                                                  const float* __restrict__ f_src2,
                                                  const float* __restrict__ f_dst2,
                                                  float* __restrict__ out) {
    __shared__ float attn[MAXNBR];
    __shared__ int nbr[MAXNBR];
    int i = blockIdx.x;
    int l = threadIdx.x;
    int cnt = nbr_cnt[i];
    float fsi = f_src2[i];
    for (int j = l; j < MAXNBR; j += 64) {
        float e = -INFINITY;
        if (j < cnt) {
            int jj = nbr_idx[i * MAXNBR + j];
            nbr[j] = jj;
            float x = fsi + f_dst2[jj];
            e = x > 0.f ? x : ALPHA * x;
        }
        attn[j] = e;
    }
    __syncthreads();
    float m = fmaxf(attn[l], attn[l + 64]);
    #pragma unroll
    for (int off = 1; off < 64; off <<= 1) m = fmaxf(m, __shfl_xor(m, off));
    float s = 0.f;
    {
        float e0 = attn[l], e1 = attn[l + 64];
        if (e0 != -INFINITY) s += __expf(e0 - m);
        if (e1 != -INFINITY) s += __expf(e1 - m);
    }
    #pragma unroll
    for (int off = 1; off < 64; off <<= 1) s += __shfl_xor(s, off);
    for (int j = l; j < MAXNBR; j += 64) {
        float e = attn[j];
        attn[j] = (e == -INFINITY) ? 0.f : __expf(e - m) / s;
    }
    __syncthreads();
    if (l < 16) {
        float acc = 0.f;
        for (int j = 0; j < cnt; ++j)
            acc += attn[j] * h2[nbr[j] * 16 + l];
        float v = acc > 0.f ? acc : expm1f(acc);
        float mx = v;
        #pragma unroll
        for (int off = 1; off < 16; off <<= 1) mx = fmaxf(mx, __shfl_xor(mx, off));
        float se = __expf(v - mx);
        #pragma unroll
        for (int off = 1; off < 16; off <<= 1) se += __shfl_xor(se, off);
        out[i * 16 + l] = v - mx - logf(se);
    }
}

extern "C" void kernel_launch(void* const* d_in, const int* in_sizes, int n_in,
                              void* d_out, int out_size, void* d_ws, size_t ws_size,
                              hipStream_t stream) {
    const float* x      = (const float*)d_in[0];
    const float* adj    = (const float*)d_in[1];
    const float* W1     = (const float*)d_in[2];
    const float* a_src1 = (const float*)d_in[3];
    const float* a_dst1 = (const float*)d_in[4];
    const float* W2     = (const float*)d_in[5];
    const float* a_src2 = (const float*)d_in[6];
    const float* a_dst2 = (const float*)d_in[7];
    float* out = (float*)d_out;

    char* ws = (char*)d_ws;
    unsigned short* xb    = (unsigned short*)ws;                      // 4 MB
    unsigned short* w1t   = (unsigned short*)(ws + (4u << 20));       // 1 MB
    unsigned short* h1b   = (unsigned short*)(ws + (5u << 20));       // 8 MB
    unsigned short* h1act = (unsigned short*)(ws + (13u << 20));      // 8 MB
    float* fsrc1 = (float*)(ws + (21u << 20));                        // 128 KB
    float* fdst1 = (float*)(ws + (21u << 20) + (128u << 10));         // 128 KB
    float* h2    = (float*)(ws + (22u << 20));                        // 256 KB
    float* fsrc2 = (float*)(ws + (22u << 20) + (256u << 10));         // 16 KB
    float* fdst2 = (float*)(ws + (22u << 20) + (272u << 10));         // 16 KB
    int* nbr_idx = (int*)(ws + (23u << 20));                          // 2 MB
    int* nbr_cnt = (int*)(ws + (25u << 20));                          // 16 KB

    build_adj<<<1024, 256, 0, stream>>>(adj, nbr_idx, nbr_cnt);
    cvt_inputs<<<4096, 256, 0, stream>>>(x, xb, W1, w1t);
    gemm1<<<dim3(32, 8), 256, 0, stream>>>(xb, w1t, h1b);
    attn_coef1<<<4096, 256, 0, stream>>>(h1b, a_src1, a_dst1, fsrc1, fdst1);
    aggregate1<<<4096, 256, 0, stream>>>(h1b, nbr_idx, nbr_cnt, fsrc1, fdst1, h1act);
    layer2_gemm<<<4096, 256, 0, stream>>>(h1act, W2, a_src2, a_dst2, h2, fsrc2, fdst2);
    final_layer<<<4096, 64, 0, stream>>>(h2, nbr_idx, nbr_cnt, fsrc2, fdst2, out);
}

// Round 3
// 81.852 us; speedup vs baseline: 1.4265x; 1.0406x over previous
//
#include <hip/hip_runtime.h>
#include <hip/hip_bf16.h>

typedef __attribute__((ext_vector_type(8))) short short8;
typedef __attribute__((ext_vector_type(4))) float f32x4;

#define MAXNBR 128
#define ALPHA 0.2f

static __device__ __forceinline__ unsigned short f2bf(float f) {
    union { float f; unsigned u; } v; v.f = f;
    unsigned r = v.u + 0x7FFF + ((v.u >> 16) & 1);
    return (unsigned short)(r >> 16);
}
static __device__ __forceinline__ float bf2f(unsigned short u) {
    union { unsigned u; float f; } v; v.u = ((unsigned)u) << 16;
    return v.f;
}

// ---------- K0: prep — build_adj + cvt x + cvt W1t + cvt W2 (range dispatch) ----------
__global__ __launch_bounds__(256) void prep(const float* __restrict__ adj,
                                            int* __restrict__ nbr_idx,
                                            int* __restrict__ nbr_cnt,
                                            const float* __restrict__ x,
                                            unsigned short* __restrict__ xb,
                                            const float* __restrict__ W1,
                                            unsigned short* __restrict__ W1t,
                                            const float* __restrict__ W2,
                                            unsigned short* __restrict__ W2b) {
    int b = blockIdx.x;
    if (b < 1024) {
        // build_adj: 4 rows per block, one wave each
        int row = b * 4 + (threadIdx.x >> 6);
        int lane = threadIdx.x & 63;
        const float* arow = adj + (size_t)row * 4096;
        int cnt = 0;
        for (int base = 0; base < 4096; base += 256) {
            float4 v = *(const float4*)&arow[base + lane * 4];
            #pragma unroll
            for (int s = 0; s < 4; ++s) {
                float xv = ((const float*)&v)[s];
                unsigned long long m = __ballot(xv > 0.f);
                if (xv > 0.f) {
                    int pos = cnt + (int)__popcll(m & ((1ull << lane) - 1ull));
                    if (pos < MAXNBR) nbr_idx[row * MAXNBR + pos] = base + lane * 4 + s;
                }
                cnt += (int)__popcll(m);
            }
        }
        if (lane == 0) nbr_cnt[row] = cnt < MAXNBR ? cnt : MAXNBR;
    } else if (b < 3072) {
        int idx = (b - 1024) * 256 + threadIdx.x;   // one per 4 elems of x
        float4 v = *(const float4*)&x[(size_t)idx * 4];
        ushort4 o;
        o.x = f2bf(v.x); o.y = f2bf(v.y); o.z = f2bf(v.z); o.w = f2bf(v.w);
        *(ushort4*)&xb[(size_t)idx * 4] = o;
    } else if (b < 5120) {
        int idx = (b - 3072) * 256 + threadIdx.x;  // output index c*512+k
        int c = idx >> 9, k = idx & 511;
        W1t[idx] = f2bf(W1[(size_t)k * 1024 + c]);
    } else {
        int idx = (b - 5120) * 256 + threadIdx.x;  // 16384 elems
        W2b[idx] = f2bf(W2[idx]);
    }
}

// ---------- K1: h1b[4096][1024] bf16 = xb[4096][512] @ W1t ; BM=128 BN=64 ----------
__global__ __launch_bounds__(256) void gemm1(const unsigned short* __restrict__ A,
                                             const unsigned short* __restrict__ Bt,
                                             unsigned short* __restrict__ C) {
    __shared__ unsigned short Asm[128 * 64];   // 16 KB
    __shared__ unsigned short Bsm[64 * 64];    //  8 KB
    int tid = threadIdx.x;
    int lane = tid & 63;
    int w = tid >> 6;
    int wr = w >> 1, wc = w & 1;               // waves 2x2; wave tile 64x32
    int rowBase = blockIdx.x * 128, colBase = blockIdx.y * 64;
    int lr = lane >> 3;         // row within 8-row group
    int lc = (lane & 7) * 8;    // col (bf16 units)
    f32x4 acc[4][2] = {};
    for (int k0 = 0; k0 < 512; k0 += 64) {
        #pragma unroll
        for (int i = 0; i < 4; ++i) {
            int rA = i * 32 + w * 8;   // wave-uniform LDS row base
            __builtin_amdgcn_global_load_lds(
                (const __attribute__((address_space(1))) void*)&A[(size_t)(rowBase + rA + lr) * 512 + k0 + lc],
                (__attribute__((address_space(3))) void*)&Asm[rA * 64],
                16, 0, 0);
        }
        #pragma unroll
        for (int i = 0; i < 2; ++i) {
            int rB = i * 32 + w * 8;
            __builtin_amdgcn_global_load_lds(
                (const __attribute__((address_space(1))) void*)&Bt[(size_t)(colBase + rB + lr) * 512 + k0 + lc],
                (__attribute__((address_space(3))) void*)&Bsm[rB * 64],
                16, 0, 0);
        }
        __syncthreads();
        #pragma unroll
        for (int kk = 0; kk < 64; kk += 32) {
            short8 af[4], bfv[2];
            int kf = kk + (lane >> 4) * 8;
            #pragma unroll
            for (int m = 0; m < 4; ++m)
                af[m] = *(const short8*)&Asm[(wr * 64 + m * 16 + (lane & 15)) * 64 + kf];
            #pragma unroll
            for (int n = 0; n < 2; ++n)
                bfv[n] = *(const short8*)&Bsm[(wc * 32 + n * 16 + (lane & 15)) * 64 + kf];
            #pragma unroll
            for (int m = 0; m < 4; ++m)
                #pragma unroll
                for (int n = 0; n < 2; ++n)
                    acc[m][n] = __builtin_amdgcn_mfma_f32_16x16x32_bf16(af[m], bfv[n], acc[m][n], 0, 0, 0);
        }
        __syncthreads();
    }
    int crow0 = rowBase + wr * 64, ccol0 = colBase + wc * 32;
    #pragma unroll
    for (int m = 0; m < 4; ++m)
        #pragma unroll
        for (int n = 0; n < 2; ++n) {
            int col = ccol0 + n * 16 + (lane & 15);
            int row0 = crow0 + m * 16 + (lane >> 4) * 4;
            #pragma unroll
            for (int r = 0; r < 4; ++r)
                C[(size_t)(row0 + r) * 1024 + col] = f2bf(acc[m][n][r]);
        }
}

// ---------- K2: f_src1/f_dst1 [8][4096] from bf16 h1 ----------
__global__ __launch_bounds__(256) void attn_coef1(const unsigned short* __restrict__ h1b,
                                                  const float* __restrict__ a_src,
                                                  const float* __restrict__ a_dst,
                                                  float* __restrict__ f_src,
                                                  float* __restrict__ f_dst) {
    int n = blockIdx.x, t = threadIdx.x;
    ushort4 v = *(const ushort4*)&h1b[(size_t)n * 1024 + t * 4];
    int head = t >> 5;
    int o0 = (t * 4) & 127;
    float hv0 = bf2f(v.x), hv1 = bf2f(v.y), hv2 = bf2f(v.z), hv3 = bf2f(v.w);
    float ps = hv0 * a_src[head * 128 + o0] + hv1 * a_src[head * 128 + o0 + 1]
             + hv2 * a_src[head * 128 + o0 + 2] + hv3 * a_src[head * 128 + o0 + 3];
    float pd = hv0 * a_dst[head * 128 + o0] + hv1 * a_dst[head * 128 + o0 + 1]
             + hv2 * a_dst[head * 128 + o0 + 2] + hv3 * a_dst[head * 128 + o0 + 3];
    #pragma unroll
    for (int off = 1; off < 32; off <<= 1) {
        ps += __shfl_xor(ps, off);
        pd += __shfl_xor(pd, off);
    }
    if ((t & 31) == 0) {
        f_src[head * 4096 + n] = ps;
        f_dst[head * 4096 + n] = pd;
    }
}

// ---------- K3: layer-1 softmax+aggregate+elu  FUSED with layer-2 GEMM + attn coefs ----------
__global__ __launch_bounds__(256) void aggregate_fused(const unsigned short* __restrict__ h1b,
                                                       const int* __restrict__ nbr_idx,
                                                       const int* __restrict__ nbr_cnt,
                                                       const float* __restrict__ f_src,
                                                       const float* __restrict__ f_dst,
                                                       const unsigned short* __restrict__ W2b,
                                                       const float* __restrict__ a_src2,
                                                       const float* __restrict__ a_dst2,
                                                       float* __restrict__ h2,
                                                       float* __restrict__ f_src2,
                                                       float* __restrict__ f_dst2) {
    __shared__ int nbr[MAXNBR];          // element offsets (idx*1024)
    __shared__ float attw[8][MAXNBR];
    __shared__ float fs[8];
    __shared__ float red[8][2];
    __shared__ float pr[256 * 16];       // 16 KB reduce buffer
    int i = blockIdx.x;
    int t = threadIdx.x;
    int cnt = nbr_cnt[i];
    if (t < cnt) nbr[t] = nbr_idx[i * MAXNBR + t] << 10;
    if (t < 8) fs[t] = f_src[t * 4096 + i];
    __syncthreads();
    for (int p = t; p < 8 * MAXNBR; p += 256) {
        int h = p >> 7, j = p & 127;
        float e = -INFINITY;
        if (j < cnt) {
            float xv = fs[h] + f_dst[h * 4096 + (nbr[j] >> 10)];
            e = xv > 0.f ? xv : ALPHA * xv;
        }
        attw[h][j] = e;
    }
    __syncthreads();
    {
        int h = t >> 5, il = t & 31;
        float m = -INFINITY;
        for (int j = il; j < MAXNBR; j += 32) m = fmaxf(m, attw[h][j]);
        #pragma unroll
        for (int off = 1; off < 32; off <<= 1) m = fmaxf(m, __shfl_xor(m, off));
        float s = 0.f;
        for (int j = il; j < MAXNBR; j += 32) {
            float e = attw[h][j];
            if (e != -INFINITY) s += __expf(e - m);
        }
        #pragma unroll
        for (int off = 1; off < 32; off <<= 1) s += __shfl_xor(s, off);
        if (il == 0) { red[h][0] = m; red[h][1] = s; }
    }
    __syncthreads();
    for (int p = t; p < 8 * MAXNBR; p += 256) {
        int h = p >> 7, j = p & 127;
        float e = attw[h][j];
        attw[h][j] = (e == -INFINITY) ? 0.f : __expf(e - red[h][0]) / red[h][1];
    }
    __syncthreads();
    // gather: thread t owns features t*4 .. t*4+3 (head t>>5)
    int h = t >> 5;
    const unsigned short* src = h1b + t * 4;
    float a0 = 0.f, a1 = 0.f, a2 = 0.f, a3 = 0.f;
    for (int j = 0; j < cnt; ++j) {
        float wgt = attw[h][j];
        ushort4 v = *(const ushort4*)&src[(size_t)nbr[j]];
        a0 += wgt * bf2f(v.x);
        a1 += wgt * bf2f(v.y);
        a2 += wgt * bf2f(v.z);
        a3 += wgt * bf2f(v.w);
    }
    a0 = a0 > 0.f ? a0 : expm1f(a0);
    a1 = a1 > 0.f ? a1 : expm1f(a1);
    a2 = a2 > 0.f ? a2 : expm1f(a2);
    a3 = a3 > 0.f ? a3 : expm1f(a3);
    // layer-2 partial dot: po[o] = sum_r v_r * W2[t*4+r][o]
    float po[16];
    #pragma unroll
    for (int o = 0; o < 16; ++o) po[o] = 0.f;
    float vr[4] = {a0, a1, a2, a3};
    #pragma unroll
    for (int r = 0; r < 4; ++r) {
        short8 lo = *(const short8*)&W2b[(size_t)(t * 4 + r) * 16];
        short8 hi = *(const short8*)&W2b[(size_t)(t * 4 + r) * 16 + 8];
        #pragma unroll
        for (int o = 0; o < 8; ++o) {
            po[o]     += vr[r] * bf2f((unsigned short)lo[o]);
            po[o + 8] += vr[r] * bf2f((unsigned short)hi[o]);
        }
    }
    #pragma unroll
    for (int o = 0; o < 16; ++o) pr[t * 16 + o] = po[o];
    __syncthreads();
    // stage 1: 256 threads reduce 16 rows each
    {
        int o = t & 15, chunk = t >> 4;
        float s1 = 0.f;
        #pragma unroll
        for (int k = 0; k < 16; ++k) s1 += pr[(chunk * 16 + k) * 16 + o];
        __syncthreads();
        pr[chunk * 16 + o] = s1;
    }
    __syncthreads();
    if (t < 16) {
        float s2 = 0.f;
        #pragma unroll
        for (int k = 0; k < 16; ++k) s2 += pr[k * 16 + t];
        h2[i * 16 + t] = s2;
        float ps = s2 * a_src2[t];
        float pd = s2 * a_dst2[t];
        #pragma unroll
        for (int off = 1; off < 16; off <<= 1) {
            ps += __shfl_xor(ps, off);
            pd += __shfl_xor(pd, off);
        }
        if (t == 0) { f_src2[i] = ps; f_dst2[i] = pd; }
    }
}

// ---------- K4: layer-2 aggregation + elu + log_softmax ----------
__global__ __launch_bounds__(64) void final_layer(const float* __restrict__ h2,
                                                  const int* __restrict__ nbr_idx,
                                                  const int* __restrict__ nbr_cnt,
                                                  const float* __restrict__ f_src2,
                                                  const float* __restrict__ f_dst2,
                                                  float* __restrict__ out) {
    __shared__ float attn[MAXNBR];
    __shared__ int nbr[MAXNBR];
    int i = blockIdx.x;
    int l = threadIdx.x;
    int cnt = nbr_cnt[i];
    float fsi = f_src2[i];
    for (int j = l; j < MAXNBR; j += 64) {
        float e = -INFINITY;
        if (j < cnt) {
            int jj = nbr_idx[i * MAXNBR + j];
            nbr[j] = jj;
            float xv = fsi + f_dst2[jj];
            e = xv > 0.f ? xv : ALPHA * xv;
        }
        attn[j] = e;
    }
    __syncthreads();
    float m = fmaxf(attn[l], attn[l + 64]);
    #pragma unroll
    for (int off = 1; off < 64; off <<= 1) m = fmaxf(m, __shfl_xor(m, off));
    float s = 0.f;
    {
        float e0 = attn[l], e1 = attn[l + 64];
        if (e0 != -INFINITY) s += __expf(e0 - m);
        if (e1 != -INFINITY) s += __expf(e1 - m);
    }
    #pragma unroll
    for (int off = 1; off < 64; off <<= 1) s += __shfl_xor(s, off);
    for (int j = l; j < MAXNBR; j += 64) {
        float e = attn[j];
        attn[j] = (e == -INFINITY) ? 0.f : __expf(e - m) / s;
    }
    __syncthreads();
    if (l < 16) {
        float acc = 0.f;
        for (int j = 0; j < cnt; ++j)
            acc += attn[j] * h2[nbr[j] * 16 + l];
        float v = acc > 0.f ? acc : expm1f(acc);
        float mx = v;
        #pragma unroll
        for (int off = 1; off < 16; off <<= 1) mx = fmaxf(mx, __shfl_xor(mx, off));
        float se = __expf(v - mx);
        #pragma unroll
        for (int off = 1; off < 16; off <<= 1) se += __shfl_xor(se, off);
        out[i * 16 + l] = v - mx - logf(se);
    }
}

extern "C" void kernel_launch(void* const* d_in, const int* in_sizes, int n_in,
                              void* d_out, int out_size, void* d_ws, size_t ws_size,
                              hipStream_t stream) {
    const float* x      = (const float*)d_in[0];
    const float* adj    = (const float*)d_in[1];
    const float* W1     = (const float*)d_in[2];
    const float* a_src1 = (const float*)d_in[3];
    const float* a_dst1 = (const float*)d_in[4];
    const float* W2     = (const float*)d_in[5];
    const float* a_src2 = (const float*)d_in[6];
    const float* a_dst2 = (const float*)d_in[7];
    float* out = (float*)d_out;

    char* ws = (char*)d_ws;
    unsigned short* xb    = (unsigned short*)ws;                      // 4 MB
    unsigned short* w1t   = (unsigned short*)(ws + (4u << 20));       // 1 MB
    unsigned short* w2b   = (unsigned short*)(ws + (5u << 20));       // 32 KB
    unsigned short* h1b   = (unsigned short*)(ws + (6u << 20));       // 8 MB
    float* fsrc1 = (float*)(ws + (14u << 20));                        // 128 KB
    float* fdst1 = (float*)(ws + (14u << 20) + (128u << 10));         // 128 KB
    float* h2    = (float*)(ws + (15u << 20));                        // 256 KB
    float* fsrc2 = (float*)(ws + (15u << 20) + (256u << 10));         // 16 KB
    float* fdst2 = (float*)(ws + (15u << 20) + (272u << 10));         // 16 KB
    int* nbr_idx = (int*)(ws + (16u << 20));                          // 2 MB
    int* nbr_cnt = (int*)(ws + (18u << 20));                          // 16 KB

    prep<<<5184, 256, 0, stream>>>(adj, nbr_idx, nbr_cnt, x, xb, W1, w1t, W2, w2b);
    gemm1<<<dim3(32, 16), 256, 0, stream>>>(xb, w1t, h1b);
    attn_coef1<<<4096, 256, 0, stream>>>(h1b, a_src1, a_dst1, fsrc1, fdst1);
    aggregate_fused<<<4096, 256, 0, stream>>>(h1b, nbr_idx, nbr_cnt, fsrc1, fdst1,
                                              w2b, a_src2, a_dst2, h2, fsrc2, fdst2);
    final_layer<<<4096, 64, 0, stream>>>(h2, nbr_idx, nbr_cnt, fsrc2, fdst2, out);
}

// Round 4
// 71.179 us; speedup vs baseline: 1.6404x; 1.1500x over previous
//
#include <hip/hip_runtime.h>
#include <hip/hip_bf16.h>

typedef __attribute__((ext_vector_type(8))) short short8;
typedef __attribute__((ext_vector_type(4))) float f32x4;

#define MAXNBR 128
#define ALPHA 0.2f

static __device__ __forceinline__ unsigned short f2bf(float f) {
    union { float f; unsigned u; } v; v.f = f;
    unsigned r = v.u + 0x7FFF + ((v.u >> 16) & 1);
    return (unsigned short)(r >> 16);
}
static __device__ __forceinline__ float bf2f(unsigned short u) {
    union { unsigned u; float f; } v; v.u = ((unsigned)u) << 16;
    return v.f;
}

// ---------- K0: cvt x -> bf16, W1 -> W1t bf16, W2 -> bf16 ----------
__global__ __launch_bounds__(256) void cvt(const float* __restrict__ x,
                                           unsigned short* __restrict__ xb,
                                           const float* __restrict__ W1,
                                           unsigned short* __restrict__ W1t,
                                           const float* __restrict__ W2,
                                           unsigned short* __restrict__ W2b) {
    int b = blockIdx.x, t = threadIdx.x;
    if (b < 1024) {                       // x: 8 elems/thread
        size_t base = (size_t)b * 2048 + t * 8;
        float4 v0 = *(const float4*)&x[base];
        float4 v1 = *(const float4*)&x[base + 4];
        short8 o;
        o[0] = f2bf(v0.x); o[1] = f2bf(v0.y); o[2] = f2bf(v0.z); o[3] = f2bf(v0.w);
        o[4] = f2bf(v1.x); o[5] = f2bf(v1.y); o[6] = f2bf(v1.z); o[7] = f2bf(v1.w);
        *(short8*)&xb[base] = o;
    } else if (b < 3072) {                // W1t transpose: 1 elem/thread
        int idx = (b - 1024) * 256 + t;   // out index c*512+k
        int c = idx >> 9, k = idx & 511;
        W1t[idx] = f2bf(W1[(size_t)k * 1024 + c]);
    } else {                              // W2: 16384 elems, 1/thread, 64 blocks
        int idx = (b - 3072) * 256 + t;
        W2b[idx] = f2bf(W2[idx]);
    }
}

// ---------- K1: fused GEMM (512 blocks) + adjacency scan (1024 blocks) ----------
__global__ __launch_bounds__(256) void gemm_scan(const unsigned short* __restrict__ A,
                                                 const unsigned short* __restrict__ Bt,
                                                 unsigned short* __restrict__ C,
                                                 const float* __restrict__ adj,
                                                 int* __restrict__ nbr_idx,
                                                 int* __restrict__ nbr_cnt) {
    __shared__ unsigned short Asm[128 * 64];   // 16 KB
    __shared__ unsigned short Bsm[64 * 64];    //  8 KB
    int b = blockIdx.x;
    int tid = threadIdx.x;
    if (b < 512) {
        // ----- GEMM: h1b[4096][1024] = xb[4096][512] @ W1t; BM=128 BN=64 -----
        int lane = tid & 63;
        int w = tid >> 6;
        int wr = w >> 1, wc = w & 1;           // waves 2x2; wave tile 64x32
        int rowBase = (b & 31) * 128, colBase = (b >> 5) * 64;
        int lr = lane >> 3;
        int lc = (lane & 7) * 8;
        f32x4 acc[4][2] = {};
        for (int k0 = 0; k0 < 512; k0 += 64) {
            #pragma unroll
            for (int i = 0; i < 4; ++i) {
                int rA = i * 32 + w * 8;
                __builtin_amdgcn_global_load_lds(
                    (const __attribute__((address_space(1))) void*)&A[(size_t)(rowBase + rA + lr) * 512 + k0 + lc],
                    (__attribute__((address_space(3))) void*)&Asm[rA * 64],
                    16, 0, 0);
            }
            #pragma unroll
            for (int i = 0; i < 2; ++i) {
                int rB = i * 32 + w * 8;
                __builtin_amdgcn_global_load_lds(
                    (const __attribute__((address_space(1))) void*)&Bt[(size_t)(colBase + rB + lr) * 512 + k0 + lc],
                    (__attribute__((address_space(3))) void*)&Bsm[rB * 64],
                    16, 0, 0);
            }
            __syncthreads();
            #pragma unroll
            for (int kk = 0; kk < 64; kk += 32) {
                short8 af[4], bfv[2];
                int kf = kk + (lane >> 4) * 8;
                #pragma unroll
                for (int m = 0; m < 4; ++m)
                    af[m] = *(const short8*)&Asm[(wr * 64 + m * 16 + (lane & 15)) * 64 + kf];
                #pragma unroll
                for (int n = 0; n < 2; ++n)
                    bfv[n] = *(const short8*)&Bsm[(wc * 32 + n * 16 + (lane & 15)) * 64 + kf];
                #pragma unroll
                for (int m = 0; m < 4; ++m)
                    #pragma unroll
                    for (int n = 0; n < 2; ++n)
                        acc[m][n] = __builtin_amdgcn_mfma_f32_16x16x32_bf16(af[m], bfv[n], acc[m][n], 0, 0, 0);
            }
            __syncthreads();
        }
        int crow0 = rowBase + wr * 64, ccol0 = colBase + wc * 32;
        #pragma unroll
        for (int m = 0; m < 4; ++m)
            #pragma unroll
            for (int n = 0; n < 2; ++n) {
                int col = ccol0 + n * 16 + (lane & 15);
                int row0 = crow0 + m * 16 + (lane >> 4) * 4;
                #pragma unroll
                for (int r = 0; r < 4; ++r)
                    C[(size_t)(row0 + r) * 1024 + col] = f2bf(acc[m][n][r]);
            }
    } else {
        // ----- adjacency scan: 4 rows/block, one wave each -----
        int row = (b - 512) * 4 + (tid >> 6);
        int lane = tid & 63;
        const float* arow = adj + (size_t)row * 4096;
        int cnt = 0;
        for (int base = 0; base < 4096; base += 256) {
            float4 v = *(const float4*)&arow[base + lane * 4];
            #pragma unroll
            for (int s = 0; s < 4; ++s) {
                float xv = ((const float*)&v)[s];
                unsigned long long m = __ballot(xv > 0.f);
                if (xv > 0.f) {
                    int pos = cnt + (int)__popcll(m & ((1ull << lane) - 1ull));
                    if (pos < MAXNBR) nbr_idx[row * MAXNBR + pos] = base + lane * 4 + s;
                }
                cnt += (int)__popcll(m);
            }
        }
        if (lane == 0) nbr_cnt[row] = cnt < MAXNBR ? cnt : MAXNBR;
    }
}

// ---------- K2: f_src1/f_dst1 [8][4096] from bf16 h1 ----------
__global__ __launch_bounds__(256) void attn_coef1(const unsigned short* __restrict__ h1b,
                                                  const float* __restrict__ a_src,
                                                  const float* __restrict__ a_dst,
                                                  float* __restrict__ f_src,
                                                  float* __restrict__ f_dst) {
    int n = blockIdx.x, t = threadIdx.x;
    ushort4 v = *(const ushort4*)&h1b[(size_t)n * 1024 + t * 4];
    int head = t >> 5;
    int o0 = (t * 4) & 127;
    float hv0 = bf2f(v.x), hv1 = bf2f(v.y), hv2 = bf2f(v.z), hv3 = bf2f(v.w);
    float ps = hv0 * a_src[head * 128 + o0] + hv1 * a_src[head * 128 + o0 + 1]
             + hv2 * a_src[head * 128 + o0 + 2] + hv3 * a_src[head * 128 + o0 + 3];
    float pd = hv0 * a_dst[head * 128 + o0] + hv1 * a_dst[head * 128 + o0 + 1]
             + hv2 * a_dst[head * 128 + o0 + 2] + hv3 * a_dst[head * 128 + o0 + 3];
    #pragma unroll
    for (int off = 1; off < 32; off <<= 1) {
        ps += __shfl_xor(ps, off);
        pd += __shfl_xor(pd, off);
    }
    if ((t & 31) == 0) {
        f_src[head * 4096 + n] = ps;
        f_dst[head * 4096 + n] = pd;
    }
}

// ---------- K3: layer-1 softmax + gather + elu + layer-2 GEMM + attn coefs ----------
__global__ __launch_bounds__(256) void aggregate_fused(const unsigned short* __restrict__ h1b,
                                                       const int* __restrict__ nbr_idx,
                                                       const int* __restrict__ nbr_cnt,
                                                       const float* __restrict__ f_src,
                                                       const float* __restrict__ f_dst,
                                                       const unsigned short* __restrict__ W2b,
                                                       const float* __restrict__ a_src2,
                                                       const float* __restrict__ a_dst2,
                                                       float* __restrict__ h2,
                                                       float* __restrict__ f_src2,
                                                       float* __restrict__ f_dst2) {
    __shared__ int nbr[MAXNBR];
    __shared__ float attw[8][MAXNBR];
    __shared__ float fs[8];
    __shared__ float hrow[1024];         // 4 KB, fp32 h1act row
    __shared__ float partial[16][16];
    int i = blockIdx.x;
    int t = threadIdx.x;
    int cnt = nbr_cnt[i];                // uniform scalar load
    if (t < MAXNBR) nbr[t] = (t < cnt) ? nbr_idx[i * MAXNBR + t] : 0;
    if (t < 8) fs[t] = f_src[t * 4096 + i];
    __syncthreads();
    // ---- one-pass softmax: thread t -> head t>>5, slots (t&31)+32q ----
    {
        int h = t >> 5, sl = t & 31;
        float fsh = fs[h];
        float e[4];
        #pragma unroll
        for (int q = 0; q < 4; ++q) {
            int j = sl + q * 32;
            if (j < cnt) {
                float xv = fsh + f_dst[h * 4096 + nbr[j]];
                e[q] = xv > 0.f ? xv : ALPHA * xv;
            } else e[q] = -INFINITY;
        }
        float m = fmaxf(fmaxf(e[0], e[1]), fmaxf(e[2], e[3]));
        #pragma unroll
        for (int off = 1; off < 32; off <<= 1) m = fmaxf(m, __shfl_xor(m, off));
        float wq[4];
        float s = 0.f;
        #pragma unroll
        for (int q = 0; q < 4; ++q) {
            wq[q] = (e[q] == -INFINITY) ? 0.f : __expf(e[q] - m);
            s += wq[q];
        }
        #pragma unroll
        for (int off = 1; off < 32; off <<= 1) s += __shfl_xor(s, off);
        float inv = 1.f / s;
        #pragma unroll
        for (int q = 0; q < 4; ++q) attw[h][sl + q * 32] = wq[q] * inv;
    }
    __syncthreads();
    // ---- gather (8-deep unrolled for MLP), thread t -> feats t*4..t*4+3 ----
    int h = t >> 5;
    const unsigned short* src = h1b + t * 4;
    float a0 = 0.f, a1 = 0.f, a2 = 0.f, a3 = 0.f;
    int cntPad = (cnt + 7) & ~7;
    for (int j = 0; j < cntPad; j += 8) {
        int4 nb0 = *(const int4*)&nbr[j];
        int4 nb1 = *(const int4*)&nbr[j + 4];
        float4 w0 = *(const float4*)&attw[h][j];
        float4 w1 = *(const float4*)&attw[h][j + 4];
        ushort4 v0 = *(const ushort4*)&src[(size_t)nb0.x << 10];
        ushort4 v1 = *(const ushort4*)&src[(size_t)nb0.y << 10];
        ushort4 v2 = *(const ushort4*)&src[(size_t)nb0.z << 10];
        ushort4 v3 = *(const ushort4*)&src[(size_t)nb0.w << 10];
        ushort4 v4 = *(const ushort4*)&src[(size_t)nb1.x << 10];
        ushort4 v5 = *(const ushort4*)&src[(size_t)nb1.y << 10];
        ushort4 v6 = *(const ushort4*)&src[(size_t)nb1.z << 10];
        ushort4 v7 = *(const ushort4*)&src[(size_t)nb1.w << 10];
        a0 += w0.x * bf2f(v0.x) + w0.y * bf2f(v1.x) + w0.z * bf2f(v2.x) + w0.w * bf2f(v3.x)
            + w1.x * bf2f(v4.x) + w1.y * bf2f(v5.x) + w1.z * bf2f(v6.x) + w1.w * bf2f(v7.x);
        a1 += w0.x * bf2f(v0.y) + w0.y * bf2f(v1.y) + w0.z * bf2f(v2.y) + w0.w * bf2f(v3.y)
            + w1.x * bf2f(v4.y) + w1.y * bf2f(v5.y) + w1.z * bf2f(v6.y) + w1.w * bf2f(v7.y);
        a2 += w0.x * bf2f(v0.z) + w0.y * bf2f(v1.z) + w0.z * bf2f(v2.z) + w0.w * bf2f(v3.z)
            + w1.x * bf2f(v4.z) + w1.y * bf2f(v5.z) + w1.z * bf2f(v6.z) + w1.w * bf2f(v7.z);
        a3 += w0.x * bf2f(v0.w) + w0.y * bf2f(v1.w) + w0.z * bf2f(v2.w) + w0.w * bf2f(v3.w)
            + w1.x * bf2f(v4.w) + w1.y * bf2f(v5.w) + w1.z * bf2f(v6.w) + w1.w * bf2f(v7.w);
    }
    a0 = a0 > 0.f ? a0 : expm1f(a0);
    a1 = a1 > 0.f ? a1 : expm1f(a1);
    a2 = a2 > 0.f ? a2 : expm1f(a2);
    a3 = a3 > 0.f ? a3 : expm1f(a3);
    *(float4*)&hrow[t * 4] = make_float4(a0, a1, a2, a3);
    __syncthreads();
    // ---- layer-2 dot: h2row[o] = sum_k hrow[k]*W2[k][o] ----
    {
        int o = t & 15, seg = t >> 4;
        float acc = 0.f;
        #pragma unroll 8
        for (int k = seg * 64; k < seg * 64 + 64; ++k)
            acc += hrow[k] * bf2f(W2b[k * 16 + o]);
        partial[seg][o] = acc;
    }
    __syncthreads();
    if (t < 16) {
        float s2 = 0.f;
        #pragma unroll
        for (int g = 0; g < 16; ++g) s2 += partial[g][t];
        h2[i * 16 + t] = s2;
        float ps = s2 * a_src2[t];
        float pd = s2 * a_dst2[t];
        #pragma unroll
        for (int off = 1; off < 16; off <<= 1) {
            ps += __shfl_xor(ps, off);
            pd += __shfl_xor(pd, off);
        }
        if (t == 0) { f_src2[i] = ps; f_dst2[i] = pd; }
    }
}

// ---------- K4: layer-2 aggregation + elu + log_softmax ----------
__global__ __launch_bounds__(64) void final_layer(const float* __restrict__ h2,
                                                  const int* __restrict__ nbr_idx,
                                                  const int* __restrict__ nbr_cnt,
                                                  const float* __restrict__ f_src2,
                                                  const float* __restrict__ f_dst2,
                                                  float* __restrict__ out) {
    __shared__ float attn[MAXNBR];
    __shared__ int nbr[MAXNBR];
    int i = blockIdx.x;
    int l = threadIdx.x;
    int cnt = nbr_cnt[i];
    float fsi = f_src2[i];
    for (int j = l; j < MAXNBR; j += 64) {
        float e = -INFINITY;
        if (j < cnt) {
            int jj = nbr_idx[i * MAXNBR + j];
            nbr[j] = jj;
            float xv = fsi + f_dst2[jj];
            e = xv > 0.f ? xv : ALPHA * xv;
        }
        attn[j] = e;
    }
    __syncthreads();
    float m = fmaxf(attn[l], attn[l + 64]);
    #pragma unroll
    for (int off = 1; off < 64; off <<= 1) m = fmaxf(m, __shfl_xor(m, off));
    float s = 0.f;
    {
        float e0 = attn[l], e1 = attn[l + 64];
        if (e0 != -INFINITY) s += __expf(e0 - m);
        if (e1 != -INFINITY) s += __expf(e1 - m);
    }
    #pragma unroll
    for (int off = 1; off < 64; off <<= 1) s += __shfl_xor(s, off);
    for (int j = l; j < MAXNBR; j += 64) {
        float e = attn[j];
        attn[j] = (e == -INFINITY) ? 0.f : __expf(e - m) / s;
    }
    __syncthreads();
    if (l < 16) {
        float acc = 0.f;
        for (int j = 0; j < cnt; ++j)
            acc += attn[j] * h2[nbr[j] * 16 + l];
        float v = acc > 0.f ? acc : expm1f(acc);
        float mx = v;
        #pragma unroll
        for (int off = 1; off < 16; off <<= 1) mx = fmaxf(mx, __shfl_xor(mx, off));
        float se = __expf(v - mx);
        #pragma unroll
        for (int off = 1; off < 16; off <<= 1) se += __shfl_xor(se, off);
        out[i * 16 + l] = v - mx - logf(se);
    }
}

extern "C" void kernel_launch(void* const* d_in, const int* in_sizes, int n_in,
                              void* d_out, int out_size, void* d_ws, size_t ws_size,
                              hipStream_t stream) {
    const float* x      = (const float*)d_in[0];
    const float* adj    = (const float*)d_in[1];
    const float* W1     = (const float*)d_in[2];
    const float* a_src1 = (const float*)d_in[3];
    const float* a_dst1 = (const float*)d_in[4];
    const float* W2     = (const float*)d_in[5];
    const float* a_src2 = (const float*)d_in[6];
    const float* a_dst2 = (const float*)d_in[7];
    float* out = (float*)d_out;

    char* ws = (char*)d_ws;
    unsigned short* xb    = (unsigned short*)ws;                      // 4 MB
    unsigned short* w1t   = (unsigned short*)(ws + (4u << 20));       // 1 MB
    unsigned short* w2b   = (unsigned short*)(ws + (5u << 20));       // 32 KB
    unsigned short* h1b   = (unsigned short*)(ws + (6u << 20));       // 8 MB
    float* fsrc1 = (float*)(ws + (14u << 20));                        // 128 KB
    float* fdst1 = (float*)(ws + (14u << 20) + (128u << 10));         // 128 KB
    float* h2    = (float*)(ws + (15u << 20));                        // 256 KB
    float* fsrc2 = (float*)(ws + (15u << 20) + (256u << 10));         // 16 KB
    float* fdst2 = (float*)(ws + (15u << 20) + (272u << 10));         // 16 KB
    int* nbr_idx = (int*)(ws + (16u << 20));                          // 2 MB
    int* nbr_cnt = (int*)(ws + (18u << 20));                          // 16 KB

    cvt<<<3136, 256, 0, stream>>>(x, xb, W1, w1t, W2, w2b);
    gemm_scan<<<1536, 256, 0, stream>>>(xb, w1t, h1b, adj, nbr_idx, nbr_cnt);
    attn_coef1<<<4096, 256, 0, stream>>>(h1b, a_src1, a_dst1, fsrc1, fdst1);
    aggregate_fused<<<4096, 256, 0, stream>>>(h1b, nbr_idx, nbr_cnt, fsrc1, fdst1,
                                              w2b, a_src2, a_dst2, h2, fsrc2, fdst2);
    final_layer<<<4096, 64, 0, stream>>>(h2, nbr_idx, nbr_cnt, fsrc2, fdst2, out);
}